// Round 16
// baseline (206.192 us; speedup 1.0000x reference)
//
#include <hip/hip_runtime.h>
#include <hip/hip_fp16.h>

// Problem constants
#define D_  128
#define T_  128
#define P_  255           // 2T-1 evaluation points
#define SROW 8320         // 65*128 (64 hden rows + 1 fybar row)
#define GSZ  32640        // 255*128

// workspace offsets (float slots)
#define OFF_YGT   0          // half ygT[128][128]      8192 f
#define OFF_COEF  8192       // float coef[512]
#define OFF_AINV  8704       // float Ainv[16384]
#define OFF_E     41472      // half E[8160*128]        522240 f
#define OFF_HDW   563712     // half HDW[255*2080]      265200 f
#define OFF_W1T   828912     // half W1T[256][128]      16384 f
#define OFF_W2T   845296     // half W2T[128][256]      16384 f
#define OFF_WTT   861680     // half WTT[128][8320]     532480 f
#define OFF_S     1394160    // half Sh[256*8320]       1064960 f
#define OFF_G2    2459120    // float g[32640]
#define OFF_CTR   2491760    // unsigned ctr[1]
// end = 2491761 floats = 9.5 MiB

typedef _Float16 f16;
typedef _Float16 f16x4 __attribute__((ext_vector_type(4)));
typedef float f32x4 __attribute__((ext_vector_type(4)));

__device__ __forceinline__ float tanh_fast(float x) {
  float e = __expf(2.0f * x);
  return 1.0f - 2.0f / (e + 1.0f);
}

// Fragment read from swizzled row-major [rows][K] f16 LDS buffer.
__device__ __forceinline__ f16x4 ldfrag(const f16* buf, int row, int kunits,
                                        int kk, int quad) {
  int u = row * kunits + ((kk * 4 + quad) ^ (row & 7));
  return *(const f16x4*)(buf + 4 * u);
}

// ---- setup: ygT init, W1T/W2T f16 transposes, WTT relayout, Thomas inverse --
__global__ __launch_bounds__(256) void k_setup(
    const float* __restrict__ z0, const float* __restrict__ tgrid,
    const float* __restrict__ W1, const float* __restrict__ W2,
    const float* __restrict__ Wk2, const float* __restrict__ bk2,
    __half* __restrict__ ygT, float* __restrict__ coef,
    float* __restrict__ Ainv, __half* __restrict__ W1T,
    __half* __restrict__ W2T, __half* __restrict__ WTT,
    unsigned* __restrict__ ctr) {
  __shared__ __align__(16) unsigned char smem[66560];
  int bid = blockIdx.x, tid = threadIdx.x;
  for (int idx = bid * 256 + tid; idx < 65 * 16384; idx += 256 * 256) {
    int c = idx >> 14, rem = idx & 16383;
    int i = rem >> 7, j = rem & 127;
    float v = (c < 64) ? Wk2[idx] : bk2[rem];
    WTT[i * 8320 + c * 128 + j] = __float2half(v);
  }
  if (bid == 0) {
    for (int idx = tid; idx < 16384; idx += 256) {
      int grow = idx >> 7, d = idx & 127;
      ygT[d * 128 + grow] = __float2half(z0[d]);
    }
  } else if (bid == 1) {
    for (int idx = tid; idx < 32768; idx += 256) {
      int c = idx >> 7, d = idx & 127;
      W1T[idx] = __float2half(W1[d * 256 + c]);
    }
  } else if (bid == 2) {
    for (int idx = tid; idx < 32768; idx += 256) {
      int j = idx >> 8, c2 = idx & 255;
      W2T[idx] = __float2half(W2[c2 * 128 + j]);
    }
  } else if (bid == 3) {
    if (tid == 0) *ctr = 0u;
  } else if (bid == 255) {   // tridiagonal inverse (Thomas per column)
    float* dpL = (float*)smem;              // 127*128 floats
    float* tl  = (float*)(smem + 65024);    // 128
    float* cpL = tl + 128;
    float* imL = cpL + 128;
    if (tid < 128) tl[tid] = tgrid[tid];
    __syncthreads();
    if (tid == 0) {
      cpL[0] = 0.0f;
      float cprev = 0.0f;
      for (int i = 1; i <= 126; ++i) {
        float hm = tl[i] - tl[i - 1], hi = tl[i + 1] - tl[i];
        float m = 2.0f * (hm + hi) - hm * cprev;
        float im = 1.0f / m;
        imL[i] = im;
        cprev = hi * im;
        cpL[i] = cprev;
      }
    }
    if (tid < 127) coef[256 + tid] = 1.0f / (tl[tid + 1] - tl[tid]);
    __syncthreads();
    if (tid < 128) {
      int d = tid;
      float dprev = (d == 0) ? 1.0f : 0.0f;
      dpL[d] = dprev;
      for (int i = 1; i <= 126; ++i) {
        float rhs = (i == d) ? 1.0f : 0.0f;
        float hm = tl[i] - tl[i - 1];
        dprev = (rhs - hm * dprev) * imL[i];
        dpL[i * 128 + d] = dprev;
      }
      float x = (d == 127) ? 1.0f : 0.0f;
      Ainv[127 * 128 + d] = x;
      for (int i = 126; i >= 0; --i) {
        x = dpL[i * 128 + d] - cpL[i] * x;
        Ainv[i * 128 + d] = x;
      }
    }
  }
}

// Fused per-p MFMA chain, 512 threads (8 waves), T14 async-STAGE split.
// it==0 additionally computes this block's E rows + wq-folded hden table.
__global__ __launch_bounds__(512) void k_fused(
    __half* __restrict__ E, __half* __restrict__ HDW,
    const __half* __restrict__ ygT,
    const __half* __restrict__ W1T, const __half* __restrict__ W2T,
    const float* __restrict__ b1, const float* __restrict__ b2,
    __half* __restrict__ Sh, float* __restrict__ g,
    const float* __restrict__ tgrid, const float* __restrict__ Wk1,
    const float* __restrict__ bk1, const float* __restrict__ coef,
    const float* __restrict__ Ainv, int it) {
  __shared__ __align__(16) unsigned char smem[65536];
  __shared__ float tl[128], ihL[128];
  __shared__ float sn[32], an[32], bn[32], cA[32], cB[32];
  __shared__ int idn[32];
  f16* RW = (f16*)smem;              // 16384 h
  f16* RA = (f16*)(smem + 32768);    // 4096 h: E -> fyT[128 j][32 n]
  f16* RB = (f16*)(smem + 40960);    // 4096 h: ys -> hdw
  f16* RC = (f16*)(smem + 49152);    // 8192 h: h1[32][256]
  int p = blockIdx.x, tid = threadIdx.x;
  int wv = tid >> 6, l = tid & 63, quad = l >> 4, r = l & 15;

  if (tid < 128) g[p * 128 + tid] = 0.0f;
  if (p == 0) {
    unsigned* zrow = (unsigned*)(Sh + 255 * SROW);
    for (int z = tid; z < SROW / 2; z += 512) zrow[z] = 0u;
  }

  // ---- it==0 prologue: E rows + wq-folded hden (block-local) ----
  if (it == 0) {
    if (tid < 128) tl[tid] = tgrid[tid];
    if (tid < 127) ihL[tid] = coef[256 + tid];
    __syncthreads();
    float xp = (p < T_) ? tl[p] : 0.5f * (tl[p - T_] + tl[p - T_ + 1]);
    if (tid < 32) {
      int n = tid;
      float u = (float)n * (1.0f / 31.0f);
      float q = xp * u;
      float qc = fminf(fmaxf(q, tl[0]), tl[127]);
      int i = (int)floorf(qc * 127.0f);
      i = max(0, min(126, i));
      while (i > 0 && qc < tl[i]) --i;
      while (i < 126 && qc >= tl[i + 1]) ++i;
      float h = tl[i + 1] - tl[i];
      float aa = (tl[i + 1] - qc) / h, bb = (qc - tl[i]) / h;
      sn[n] = q; idn[n] = i; an[n] = aa; bn[n] = bb;
      float h26 = h * h * (1.0f / 6.0f);
      cA[n] = (aa * aa * aa - aa) * h26;
      cB[n] = (bb * bb * bb - bb) * h26;
    }
    __syncthreads();
    #pragma unroll
    for (int pass = 0; pass < 8; ++pass) {
      int n = pass * 4 + (tid >> 7);
      int b = tid & 127;
      int i = idn[n];
      float Gi = 0.0f, Gi1 = 0.0f;
      if (b >= 2) {
        float w = 6.0f * ihL[b - 1];
        Gi  += Ainv[i * 128 + b - 1] * w;
        Gi1 += Ainv[(i + 1) * 128 + b - 1] * w;
      }
      if (b >= 1 && b <= 126) {
        float w = -6.0f * (ihL[b - 1] + ihL[b]);
        Gi  += Ainv[i * 128 + b] * w;
        Gi1 += Ainv[(i + 1) * 128 + b] * w;
      }
      if (b <= 125) {
        float w = 6.0f * ihL[b];
        Gi  += Ainv[i * 128 + b + 1] * w;
        Gi1 += Ainv[(i + 1) * 128 + b + 1] * w;
      }
      float v = cA[n] * Gi + cB[n] * Gi1;
      if (b == i) v += an[n];
      if (b == i + 1) v += bn[n];
      E[(p * 32 + n) * 128 + b] = __float2half(v);
    }
    #pragma unroll
    for (int k = 0; k < 5; ++k) {
      int idx = k * 512 + tid;
      if (idx < 2080) {
        int c = idx >> 5, n = idx & 31;
        float wq = (n == 0 || n == 31) ? 0.5f : 1.0f;
        float v = (c < 64)
            ? wq * tanh_fast(fmaf(xp, Wk1[c], fmaf(sn[n], Wk1[64 + c], bk1[c])))
            : wq;
        HDW[p * 2080 + idx] = __float2half(v);
      }
    }
    __syncthreads();
  }

  uint2 pf[8];     // in-flight weight chunk (T14)
  uint2 pfh[2];    // in-flight hdw chunk
  {
    const uint2* s1 = (const uint2*)W1T;
    #pragma unroll
    for (int k = 0; k < 8; ++k) pf[k] = s1[k * 512 + tid];
  }
  {
    const uint2* src = (const uint2*)ygT;
    uint2* dst = (uint2*)RW;
    #pragma unroll
    for (int k = 0; k < 8; ++k) {
      int idx = k * 512 + tid;
      int row = idx >> 5, k4 = idx & 31;
      dst[row * 32 + (k4 ^ (row & 7))] = src[idx];
    }
    const uint2* se = (const uint2*)(E + p * 4096);
    uint2* da = (uint2*)RA;
    #pragma unroll
    for (int k = 0; k < 2; ++k) {
      int idx = k * 512 + tid;
      int row = idx >> 5, k4 = idx & 31;
      da[row * 32 + (k4 ^ (row & 7))] = se[idx];
    }
  }
  __syncthreads();
  // ys[32][128] = E @ yg
  for (int tt = wv; tt < 16; tt += 8) {
    int mt = tt >> 3, nt = tt & 7;
    f32x4 acc = {0.f, 0.f, 0.f, 0.f};
    #pragma unroll
    for (int kk = 0; kk < 8; ++kk) {
      f16x4 av = ldfrag(RA, mt * 16 + r, 32, kk, quad);
      f16x4 bv = ldfrag(RW, nt * 16 + r, 32, kk, quad);
      acc = __builtin_amdgcn_mfma_f32_16x16x16f16(av, bv, acc, 0, 0, 0);
    }
    int col = nt * 16 + r;
    #pragma unroll
    for (int i = 0; i < 4; ++i) {
      int row = mt * 16 + quad * 4 + i;
      RB[row * 128 + (col ^ ((row & 7) << 2))] = (f16)acc[i];
    }
  }
  __syncthreads();
  {
    uint2* dst = (uint2*)RW;
    #pragma unroll
    for (int k = 0; k < 8; ++k) {
      int idx = k * 512 + tid;
      int row = idx >> 5, k4 = idx & 31;
      dst[row * 32 + (k4 ^ (row & 7))] = pf[k];
    }
    const uint2* s1 = (const uint2*)(W1T + 16384);
    #pragma unroll
    for (int k = 0; k < 8; ++k) pf[k] = s1[k * 512 + tid];
  }
  __syncthreads();
  // h1 half 0
  for (int tt = wv; tt < 16; tt += 8) {
    int mt = tt >> 3, nt = tt & 7;
    f32x4 acc = {0.f, 0.f, 0.f, 0.f};
    #pragma unroll
    for (int kk = 0; kk < 8; ++kk) {
      f16x4 av = ldfrag(RB, mt * 16 + r, 32, kk, quad);
      f16x4 bv = ldfrag(RW, nt * 16 + r, 32, kk, quad);
      acc = __builtin_amdgcn_mfma_f32_16x16x16f16(av, bv, acc, 0, 0, 0);
    }
    int colg = nt * 16 + r;
    float bias = b1[colg];
    #pragma unroll
    for (int i = 0; i < 4; ++i) {
      int row = mt * 16 + quad * 4 + i;
      RC[row * 256 + (colg ^ ((row & 7) << 2))] = (f16)tanh_fast(acc[i] + bias);
    }
  }
  __syncthreads();
  {
    uint2* dst = (uint2*)RW;
    #pragma unroll
    for (int k = 0; k < 8; ++k) {
      int idx = k * 512 + tid;
      int row = idx >> 5, k4 = idx & 31;
      dst[row * 32 + (k4 ^ (row & 7))] = pf[k];
    }
    const uint2* sh_ = (const uint2*)(HDW + p * 2080);
    #pragma unroll
    for (int k = 0; k < 2; ++k) {
      int idx = k * 512 + tid;
      if (idx < 640) pfh[k] = (idx < 520) ? sh_[idx] : make_uint2(0u, 0u);
    }
    const uint2* s2 = (const uint2*)W2T;
    #pragma unroll
    for (int k = 0; k < 8; ++k) pf[k] = s2[k * 512 + tid];
  }
  __syncthreads();
  // h1 half 1
  for (int tt = wv; tt < 16; tt += 8) {
    int mt = tt >> 3, nt = tt & 7;
    f32x4 acc = {0.f, 0.f, 0.f, 0.f};
    #pragma unroll
    for (int kk = 0; kk < 8; ++kk) {
      f16x4 av = ldfrag(RB, mt * 16 + r, 32, kk, quad);
      f16x4 bv = ldfrag(RW, nt * 16 + r, 32, kk, quad);
      acc = __builtin_amdgcn_mfma_f32_16x16x16f16(av, bv, acc, 0, 0, 0);
    }
    int colg = 128 + nt * 16 + r;
    float bias = b1[colg];
    #pragma unroll
    for (int i = 0; i < 4; ++i) {
      int row = mt * 16 + quad * 4 + i;
      RC[row * 256 + (colg ^ ((row & 7) << 2))] = (f16)tanh_fast(acc[i] + bias);
    }
  }
  __syncthreads();
  {
    uint2* db = (uint2*)RB;
    #pragma unroll
    for (int k = 0; k < 2; ++k) {
      int idx = k * 512 + tid;
      if (idx < 640) {
        int row = idx >> 3, k4 = idx & 7;
        db[row * 8 + (k4 ^ (row & 7))] = pfh[k];
      }
    }
    uint2* dst = (uint2*)RW;
    #pragma unroll
    for (int k = 0; k < 8; ++k) {
      int idx = k * 512 + tid;
      int row = idx >> 6, k4 = idx & 63;
      dst[row * 64 + (k4 ^ (row & 7))] = pf[k];
    }
    const uint2* s2 = (const uint2*)(W2T + 16384);
    #pragma unroll
    for (int k = 0; k < 8; ++k) pf[k] = s2[k * 512 + tid];
  }
  __syncthreads();
  // fy half 0
  for (int tt = wv; tt < 8; tt += 8) {
    int mt = tt >> 2, nt = tt & 3;
    f32x4 acc = {0.f, 0.f, 0.f, 0.f};
    #pragma unroll
    for (int kk = 0; kk < 16; ++kk) {
      f16x4 av = ldfrag(RC, mt * 16 + r, 64, kk, quad);
      f16x4 bv = ldfrag(RW, nt * 16 + r, 64, kk, quad);
      acc = __builtin_amdgcn_mfma_f32_16x16x16f16(av, bv, acc, 0, 0, 0);
    }
    int jg = nt * 16 + r;
    float bias = b2[jg];
    #pragma unroll
    for (int i = 0; i < 4; ++i) {
      int n = mt * 16 + quad * 4 + i;
      RA[jg * 32 + (n ^ ((jg & 7) << 2))] = (f16)(acc[i] + bias);
    }
  }
  __syncthreads();
  {
    uint2* dst = (uint2*)RW;
    #pragma unroll
    for (int k = 0; k < 8; ++k) {
      int idx = k * 512 + tid;
      int row = idx >> 6, k4 = idx & 63;
      dst[row * 64 + (k4 ^ (row & 7))] = pf[k];
    }
  }
  __syncthreads();
  // fy half 1
  for (int tt = wv; tt < 8; tt += 8) {
    int mt = tt >> 2, nt = tt & 3;
    f32x4 acc = {0.f, 0.f, 0.f, 0.f};
    #pragma unroll
    for (int kk = 0; kk < 16; ++kk) {
      f16x4 av = ldfrag(RC, mt * 16 + r, 64, kk, quad);
      f16x4 bv = ldfrag(RW, nt * 16 + r, 64, kk, quad);
      acc = __builtin_amdgcn_mfma_f32_16x16x16f16(av, bv, acc, 0, 0, 0);
    }
    int jg = 64 + nt * 16 + r;
    float bias = b2[jg];
    #pragma unroll
    for (int i = 0; i < 4; ++i) {
      int n = mt * 16 + quad * 4 + i;
      RA[jg * 32 + (n ^ ((jg & 7) << 2))] = (f16)(acc[i] + bias);
    }
  }
  __syncthreads();
  // S[80][128] = hdw @ fy
  for (int tt = wv; tt < 40; tt += 8) {
    int mt = tt >> 3, nt = tt & 7;
    f32x4 acc = {0.f, 0.f, 0.f, 0.f};
    #pragma unroll
    for (int kk = 0; kk < 2; ++kk) {
      f16x4 av = ldfrag(RB, mt * 16 + r, 8, kk, quad);
      f16x4 bv = ldfrag(RA, nt * 16 + r, 8, kk, quad);
      acc = __builtin_amdgcn_mfma_f32_16x16x16f16(av, bv, acc, 0, 0, 0);
    }
    #pragma unroll
    for (int i = 0; i < 4; ++i) {
      int c = mt * 16 + quad * 4 + i;
      if (c < 65) Sh[p * SROW + c * 128 + nt * 16 + r] = __float2half(acc[i]);
    }
  }
}

// g += S @ WTT^T via MFMA, LDS-staged, 512 threads / 8 waves (16 n-cols per
// wave). Grid (16 m-tiles, 13 K-chunks of 640); last of 208 blocks runs the
// Simpson+cumsum epilogue (split-K completion via ctr).
__global__ __launch_bounds__(512) void k_gemmM(
    const __half* __restrict__ Sh, const __half* __restrict__ WTT,
    float* __restrict__ g, const float* __restrict__ t,
    const float* __restrict__ z0, __half* __restrict__ ygT,
    float* __restrict__ out, unsigned* __restrict__ ctr, int wout) {
  __shared__ __align__(16) unsigned char smem[65280];
  __shared__ unsigned lastFlag;
  uint2* Asw  = (uint2*)smem;                    // 2560 u = 20480 B
  uint2* Bsw0 = (uint2*)(smem + 20480);          // 2048 u = 16384 B
  uint2* Bsw1 = (uint2*)(smem + 36864);          // 2048 u = 16384 B
  int mt = blockIdx.x;      // 0..15
  int kc = blockIdx.y;      // 0..12
  int tid = threadIdx.x;
  int wv = tid >> 6, l = tid & 63, quad = l >> 4, r = l & 15;
  int p0 = mt * 16;
  int k0 = kc * 640;
  // stage A[16][640]: 16 rows x 160 uint2; 32 threads/row x 5 passes
  {
    int rowA = tid >> 5, cA_ = tid & 31;
    const uint2* srcA = (const uint2*)(Sh + (p0 + rowA) * SROW + k0) + cA_;
    #pragma unroll
    for (int pass = 0; pass < 5; ++pass) {
      int u4 = pass * 32 + cA_;
      Asw[rowA * 160 + (u4 ^ (rowA & 7))] = srcA[pass * 32];
    }
  }
  // stage B kb=0: 128 rows x 16 uint2; 4 per thread
  #pragma unroll
  for (int k = 0; k < 4; ++k) {
    int idx = k * 512 + tid;
    int row = idx >> 4, u4 = idx & 15;
    Bsw0[row * 16 + (u4 ^ (row & 7))] =
        *((const uint2*)(WTT + row * SROW + k0) + u4);
  }
  __syncthreads();
  f32x4 acc0 = {0.f, 0.f, 0.f, 0.f};
  int n0 = wv * 16;
  const f16* Af = (const f16*)Asw;
  for (int kb = 0; kb < 10; ++kb) {
    const f16* Bf = (const f16*)((kb & 1) ? Bsw1 : Bsw0);
    uint2* nxtB = (kb & 1) ? Bsw0 : Bsw1;
    uint2 pf[4];
    if (kb < 9) {   // prefetch next B chunk (overlaps with MFMA below)
      #pragma unroll
      for (int k = 0; k < 4; ++k) {
        int idx = k * 512 + tid;
        int row = idx >> 4, u4 = idx & 15;
        pf[k] = *((const uint2*)(WTT + row * SROW + k0 + (kb + 1) * 64) + u4);
      }
    }
    #pragma unroll
    for (int kk = 0; kk < 4; ++kk) {
      int kg4 = kb * 16 + kk * 4 + quad;
      f16x4 av = *(const f16x4*)(Af + 4 * (r * 160 + (kg4 ^ (r & 7))));
      int nr0 = n0 + r;
      f16x4 b0 = *(const f16x4*)(Bf + 4 * (nr0 * 16 + ((kk * 4 + quad) ^ (nr0 & 7))));
      acc0 = __builtin_amdgcn_mfma_f32_16x16x16f16(av, b0, acc0, 0, 0, 0);
    }
    if (kb < 9) {
      #pragma unroll
      for (int k = 0; k < 4; ++k) {
        int idx = k * 512 + tid;
        int row = idx >> 4, u4 = idx & 15;
        nxtB[row * 16 + (u4 ^ (row & 7))] = pf[k];
      }
    }
    __syncthreads();
  }
  #pragma unroll
  for (int i = 0; i < 4; ++i) {
    int p = p0 + quad * 4 + i;
    if (p < 255) atomicAdd(&g[p * 128 + n0 + r], acc0[i]);
  }
  // ---- tail-block epilogue (split-K completion pattern) ----
  __threadfence();
  if (tid == 0) {
    unsigned old = atomicAdd(ctr, 1u);
    lastFlag = (old == 207u) ? 1u : 0u;
    if (lastFlag) *ctr = 0u;
  }
  __syncthreads();
  if (!lastFlag) return;
  __threadfence();
  float* incL = (float*)smem;
  for (int idx = tid; idx < 127 * 128; idx += 512) {
    int k = idx >> 7, d = idx & 127;
    float tk = t[k], tk1 = t[k + 1];
    float h = tk1 - tk;
    float sct  = tk * (1.0f / 31.0f);
    float scm  = 0.5f * (tk + tk1) * (1.0f / 31.0f);
    float sct1 = tk1 * (1.0f / 31.0f);
    incL[idx] = h * (1.0f / 6.0f) *
        (g[k * 128 + d] * sct + 4.0f * g[(T_ + k) * 128 + d] * scm +
         g[(k + 1) * 128 + d] * sct1);
  }
  __syncthreads();
  if (tid < 128) {
    int d = tid;
    float acc = z0[d];
    ygT[d * 128] = __float2half(acc);
    if (wout) out[d] = acc;
    #pragma unroll 4
    for (int k = 0; k < 127; ++k) {
      acc += incL[k * 128 + d];
      ygT[d * 128 + k + 1] = __float2half(acc);
      if (wout) out[(k + 1) * 128 + d] = acc;
    }
  }
}

extern "C" void kernel_launch(void* const* d_in, const int* in_sizes, int n_in,
                              void* d_out, int out_size, void* d_ws, size_t ws_size,
                              hipStream_t stream) {
  const float* z0  = (const float*)d_in[0];
  const float* t   = (const float*)d_in[1];
  const float* W1  = (const float*)d_in[2];
  const float* b1  = (const float*)d_in[3];
  const float* W2  = (const float*)d_in[4];
  const float* b2  = (const float*)d_in[5];
  const float* Wk1 = (const float*)d_in[6];
  const float* bk1 = (const float*)d_in[7];
  const float* Wk2 = (const float*)d_in[8];
  const float* bk2 = (const float*)d_in[9];
  float* out = (float*)d_out;
  float* ws  = (float*)d_ws;

  __half*   ygT  = (__half*)(ws + OFF_YGT);
  float*    coef = ws + OFF_COEF;
  float*    Ainv = ws + OFF_AINV;
  __half*   E    = (__half*)(ws + OFF_E);
  __half*   HDW  = (__half*)(ws + OFF_HDW);
  __half*   W1T  = (__half*)(ws + OFF_W1T);
  __half*   W2T  = (__half*)(ws + OFF_W2T);
  __half*   WTT  = (__half*)(ws + OFF_WTT);
  __half*   Sh   = (__half*)(ws + OFF_S);
  float*    g    = ws + OFF_G2;
  unsigned* ctr  = (unsigned*)(ws + OFF_CTR);

  k_setup<<<dim3(256), dim3(256), 0, stream>>>(z0, t, W1, W2, Wk2, bk2,
                                               ygT, coef, Ainv, W1T, W2T, WTT,
                                               ctr);
  for (int it = 0; it < 3; ++it) {
    k_fused<<<dim3(255), dim3(512), 0, stream>>>(E, HDW, ygT, W1T, W2T,
                                                 b1, b2, Sh, g, t, Wk1, bk1,
                                                 coef, Ainv, it);
    k_gemmM<<<dim3(16, 13), dim3(512), 0, stream>>>(Sh, WTT, g, t, z0, ygT, out,
                                                    ctr, (it == 2) ? 1 : 0);
  }
}

// Round 17
// 180.148 us; speedup vs baseline: 1.1446x; 1.1446x over previous
//
#include <hip/hip_runtime.h>
#include <hip/hip_fp16.h>

// Problem constants
#define D_  128
#define T_  128
#define P_  255           // 2T-1 evaluation points
#define GSZ  32640        // 255*128

// workspace offsets (float slots)
#define OFF_YGT   0          // half ygT[128][128]      8192 f
#define OFF_COEF  8192       // float coef[512]
#define OFF_AINV  8704       // float Ainv[16384]
#define OFF_E     41472      // half E[8160*128]        522240 f
#define OFF_HDW   563712     // half HDW[255*2080]      265200 f
#define OFF_W1T   828912     // half W1T[256][128]      16384 f
#define OFF_W2T   845296     // half W2T[128][256]      16384 f
#define OFF_WTT   861680     // half WTC[13][10][128][64] 532480 f
#define OFF_S     1394160    // half Sq[13][256][640]   1064960 f
#define OFF_G2    2459120    // float g[32640]
#define OFF_CTR   2491760    // unsigned ctr[1]
// end = 2491761 floats = 9.5 MiB

typedef _Float16 f16;
typedef _Float16 f16x4 __attribute__((ext_vector_type(4)));
typedef float f32x4 __attribute__((ext_vector_type(4)));

__device__ __forceinline__ float tanh_fast(float x) {
  float e = __expf(2.0f * x);
  return 1.0f - 2.0f / (e + 1.0f);
}

// Fragment read from swizzled row-major [rows][K] f16 LDS buffer.
__device__ __forceinline__ f16x4 ldfrag(const f16* buf, int row, int kunits,
                                        int kk, int quad) {
  int u = row * kunits + ((kk * 4 + quad) ^ (row & 7));
  return *(const f16x4*)(buf + 4 * u);
}

// ---- setup: ygT init, W1T/W2T f16 transposes, WTC chunk-major relayout,
//      Thomas inverse ----
__global__ __launch_bounds__(256) void k_setup(
    const float* __restrict__ z0, const float* __restrict__ tgrid,
    const float* __restrict__ W1, const float* __restrict__ W2,
    const float* __restrict__ Wk2, const float* __restrict__ bk2,
    __half* __restrict__ ygT, float* __restrict__ coef,
    float* __restrict__ Ainv, __half* __restrict__ W1T,
    __half* __restrict__ W2T, __half* __restrict__ WTC,
    unsigned* __restrict__ ctr) {
  __shared__ __align__(16) unsigned char smem[66560];
  int bid = blockIdx.x, tid = threadIdx.x;
  // WTC[((kc*10+kb)*128 + i)*64 + kw] = Wk2[c][i][j] (c<64) / bk2[i][j] (c=64)
  // where k = c*128+j, kc = c/5, kr = (c%5)*128+j, kb = kr/64, kw = kr%64.
  for (int idx = bid * 256 + tid; idx < 65 * 16384; idx += 256 * 256) {
    int c = idx >> 14, rem = idx & 16383;
    int i = rem >> 7, j = rem & 127;
    float v = (c < 64) ? Wk2[idx] : bk2[rem];
    int kc = c / 5;
    int kr = (c - kc * 5) * 128 + j;
    int kb = kr >> 6, kw = kr & 63;
    WTC[(((kc * 10 + kb) << 7) + i) * 64 + kw] = __float2half(v);
  }
  if (bid == 0) {
    for (int idx = tid; idx < 16384; idx += 256) {
      int grow = idx >> 7, d = idx & 127;
      ygT[d * 128 + grow] = __float2half(z0[d]);
    }
  } else if (bid == 1) {
    for (int idx = tid; idx < 32768; idx += 256) {
      int c = idx >> 7, d = idx & 127;
      W1T[idx] = __float2half(W1[d * 256 + c]);
    }
  } else if (bid == 2) {
    for (int idx = tid; idx < 32768; idx += 256) {
      int j = idx >> 8, c2 = idx & 255;
      W2T[idx] = __float2half(W2[c2 * 128 + j]);
    }
  } else if (bid == 3) {
    if (tid == 0) *ctr = 0u;
  } else if (bid == 255) {   // tridiagonal inverse (Thomas per column)
    float* dpL = (float*)smem;              // 127*128 floats
    float* tl  = (float*)(smem + 65024);    // 128
    float* cpL = tl + 128;
    float* imL = cpL + 128;
    if (tid < 128) tl[tid] = tgrid[tid];
    __syncthreads();
    if (tid == 0) {
      cpL[0] = 0.0f;
      float cprev = 0.0f;
      for (int i = 1; i <= 126; ++i) {
        float hm = tl[i] - tl[i - 1], hi = tl[i + 1] - tl[i];
        float m = 2.0f * (hm + hi) - hm * cprev;
        float im = 1.0f / m;
        imL[i] = im;
        cprev = hi * im;
        cpL[i] = cprev;
      }
    }
    if (tid < 127) coef[256 + tid] = 1.0f / (tl[tid + 1] - tl[tid]);
    __syncthreads();
    if (tid < 128) {
      int d = tid;
      float dprev = (d == 0) ? 1.0f : 0.0f;
      dpL[d] = dprev;
      for (int i = 1; i <= 126; ++i) {
        float rhs = (i == d) ? 1.0f : 0.0f;
        float hm = tl[i] - tl[i - 1];
        dprev = (rhs - hm * dprev) * imL[i];
        dpL[i * 128 + d] = dprev;
      }
      float x = (d == 127) ? 1.0f : 0.0f;
      Ainv[127 * 128 + d] = x;
      for (int i = 126; i >= 0; --i) {
        x = dpL[i * 128 + d] - cpL[i] * x;
        Ainv[i * 128 + d] = x;
      }
    }
  }
}

// Fused per-p MFMA chain, 512 threads (8 waves), T14 async-STAGE split.
// it==0 additionally computes this block's E rows + wq-folded hden table.
// S now stored chunk-major: Sq[kc][p][kr], kc=c/5, kr=(c%5)*128+col.
__global__ __launch_bounds__(512) void k_fused(
    __half* __restrict__ E, __half* __restrict__ HDW,
    const __half* __restrict__ ygT,
    const __half* __restrict__ W1T, const __half* __restrict__ W2T,
    const float* __restrict__ b1, const float* __restrict__ b2,
    __half* __restrict__ Sq, float* __restrict__ g,
    const float* __restrict__ tgrid, const float* __restrict__ Wk1,
    const float* __restrict__ bk1, const float* __restrict__ coef,
    const float* __restrict__ Ainv, int it) {
  __shared__ __align__(16) unsigned char smem[65536];
  __shared__ float tl[128], ihL[128];
  __shared__ float sn[32], an[32], bn[32], cA[32], cB[32];
  __shared__ int idn[32];
  f16* RW = (f16*)smem;              // 16384 h
  f16* RA = (f16*)(smem + 32768);    // 4096 h: E -> fyT[128 j][32 n]
  f16* RB = (f16*)(smem + 40960);    // 4096 h: ys -> hdw
  f16* RC = (f16*)(smem + 49152);    // 8192 h: h1[32][256]
  int p = blockIdx.x, tid = threadIdx.x;
  int wv = tid >> 6, l = tid & 63, quad = l >> 4, r = l & 15;

  if (tid < 128) g[p * 128 + tid] = 0.0f;
  if (p == 0) {   // zero the p=255 pad rows in every chunk
    for (int z = tid; z < 8320; z += 512) {
      int kcS = z / 640, kr = z - kcS * 640;
      Sq[kcS * 163840 + 255 * 640 + kr] = __float2half(0.0f);
    }
  }

  // ---- it==0 prologue: E rows + wq-folded hden (block-local) ----
  if (it == 0) {
    if (tid < 128) tl[tid] = tgrid[tid];
    if (tid < 127) ihL[tid] = coef[256 + tid];
    __syncthreads();
    float xp = (p < T_) ? tl[p] : 0.5f * (tl[p - T_] + tl[p - T_ + 1]);
    if (tid < 32) {
      int n = tid;
      float u = (float)n * (1.0f / 31.0f);
      float q = xp * u;
      float qc = fminf(fmaxf(q, tl[0]), tl[127]);
      int i = (int)floorf(qc * 127.0f);
      i = max(0, min(126, i));
      while (i > 0 && qc < tl[i]) --i;
      while (i < 126 && qc >= tl[i + 1]) ++i;
      float h = tl[i + 1] - tl[i];
      float aa = (tl[i + 1] - qc) / h, bb = (qc - tl[i]) / h;
      sn[n] = q; idn[n] = i; an[n] = aa; bn[n] = bb;
      float h26 = h * h * (1.0f / 6.0f);
      cA[n] = (aa * aa * aa - aa) * h26;
      cB[n] = (bb * bb * bb - bb) * h26;
    }
    __syncthreads();
    #pragma unroll
    for (int pass = 0; pass < 8; ++pass) {
      int n = pass * 4 + (tid >> 7);
      int b = tid & 127;
      int i = idn[n];
      float Gi = 0.0f, Gi1 = 0.0f;
      if (b >= 2) {
        float w = 6.0f * ihL[b - 1];
        Gi  += Ainv[i * 128 + b - 1] * w;
        Gi1 += Ainv[(i + 1) * 128 + b - 1] * w;
      }
      if (b >= 1 && b <= 126) {
        float w = -6.0f * (ihL[b - 1] + ihL[b]);
        Gi  += Ainv[i * 128 + b] * w;
        Gi1 += Ainv[(i + 1) * 128 + b] * w;
      }
      if (b <= 125) {
        float w = 6.0f * ihL[b];
        Gi  += Ainv[i * 128 + b + 1] * w;
        Gi1 += Ainv[(i + 1) * 128 + b + 1] * w;
      }
      float v = cA[n] * Gi + cB[n] * Gi1;
      if (b == i) v += an[n];
      if (b == i + 1) v += bn[n];
      E[(p * 32 + n) * 128 + b] = __float2half(v);
    }
    #pragma unroll
    for (int k = 0; k < 5; ++k) {
      int idx = k * 512 + tid;
      if (idx < 2080) {
        int c = idx >> 5, n = idx & 31;
        float wq = (n == 0 || n == 31) ? 0.5f : 1.0f;
        float v = (c < 64)
            ? wq * tanh_fast(fmaf(xp, Wk1[c], fmaf(sn[n], Wk1[64 + c], bk1[c])))
            : wq;
        HDW[p * 2080 + idx] = __float2half(v);
      }
    }
    __syncthreads();
  }

  uint2 pf[8];     // in-flight weight chunk (T14)
  uint2 pfh[2];    // in-flight hdw chunk
  {
    const uint2* s1 = (const uint2*)W1T;
    #pragma unroll
    for (int k = 0; k < 8; ++k) pf[k] = s1[k * 512 + tid];
  }
  {
    const uint2* src = (const uint2*)ygT;
    uint2* dst = (uint2*)RW;
    #pragma unroll
    for (int k = 0; k < 8; ++k) {
      int idx = k * 512 + tid;
      int row = idx >> 5, k4 = idx & 31;
      dst[row * 32 + (k4 ^ (row & 7))] = src[idx];
    }
    const uint2* se = (const uint2*)(E + p * 4096);
    uint2* da = (uint2*)RA;
    #pragma unroll
    for (int k = 0; k < 2; ++k) {
      int idx = k * 512 + tid;
      int row = idx >> 5, k4 = idx & 31;
      da[row * 32 + (k4 ^ (row & 7))] = se[idx];
    }
  }
  __syncthreads();
  // ys[32][128] = E @ yg
  for (int tt = wv; tt < 16; tt += 8) {
    int mt = tt >> 3, nt = tt & 7;
    f32x4 acc = {0.f, 0.f, 0.f, 0.f};
    #pragma unroll
    for (int kk = 0; kk < 8; ++kk) {
      f16x4 av = ldfrag(RA, mt * 16 + r, 32, kk, quad);
      f16x4 bv = ldfrag(RW, nt * 16 + r, 32, kk, quad);
      acc = __builtin_amdgcn_mfma_f32_16x16x16f16(av, bv, acc, 0, 0, 0);
    }
    int col = nt * 16 + r;
    #pragma unroll
    for (int i = 0; i < 4; ++i) {
      int row = mt * 16 + quad * 4 + i;
      RB[row * 128 + (col ^ ((row & 7) << 2))] = (f16)acc[i];
    }
  }
  __syncthreads();
  {
    uint2* dst = (uint2*)RW;
    #pragma unroll
    for (int k = 0; k < 8; ++k) {
      int idx = k * 512 + tid;
      int row = idx >> 5, k4 = idx & 31;
      dst[row * 32 + (k4 ^ (row & 7))] = pf[k];
    }
    const uint2* s1 = (const uint2*)(W1T + 16384);
    #pragma unroll
    for (int k = 0; k < 8; ++k) pf[k] = s1[k * 512 + tid];
  }
  __syncthreads();
  // h1 half 0
  for (int tt = wv; tt < 16; tt += 8) {
    int mt = tt >> 3, nt = tt & 7;
    f32x4 acc = {0.f, 0.f, 0.f, 0.f};
    #pragma unroll
    for (int kk = 0; kk < 8; ++kk) {
      f16x4 av = ldfrag(RB, mt * 16 + r, 32, kk, quad);
      f16x4 bv = ldfrag(RW, nt * 16 + r, 32, kk, quad);
      acc = __builtin_amdgcn_mfma_f32_16x16x16f16(av, bv, acc, 0, 0, 0);
    }
    int colg = nt * 16 + r;
    float bias = b1[colg];
    #pragma unroll
    for (int i = 0; i < 4; ++i) {
      int row = mt * 16 + quad * 4 + i;
      RC[row * 256 + (colg ^ ((row & 7) << 2))] = (f16)tanh_fast(acc[i] + bias);
    }
  }
  __syncthreads();
  {
    uint2* dst = (uint2*)RW;
    #pragma unroll
    for (int k = 0; k < 8; ++k) {
      int idx = k * 512 + tid;
      int row = idx >> 5, k4 = idx & 31;
      dst[row * 32 + (k4 ^ (row & 7))] = pf[k];
    }
    const uint2* sh_ = (const uint2*)(HDW + p * 2080);
    #pragma unroll
    for (int k = 0; k < 2; ++k) {
      int idx = k * 512 + tid;
      if (idx < 640) pfh[k] = (idx < 520) ? sh_[idx] : make_uint2(0u, 0u);
    }
    const uint2* s2 = (const uint2*)W2T;
    #pragma unroll
    for (int k = 0; k < 8; ++k) pf[k] = s2[k * 512 + tid];
  }
  __syncthreads();
  // h1 half 1
  for (int tt = wv; tt < 16; tt += 8) {
    int mt = tt >> 3, nt = tt & 7;
    f32x4 acc = {0.f, 0.f, 0.f, 0.f};
    #pragma unroll
    for (int kk = 0; kk < 8; ++kk) {
      f16x4 av = ldfrag(RB, mt * 16 + r, 32, kk, quad);
      f16x4 bv = ldfrag(RW, nt * 16 + r, 32, kk, quad);
      acc = __builtin_amdgcn_mfma_f32_16x16x16f16(av, bv, acc, 0, 0, 0);
    }
    int colg = 128 + nt * 16 + r;
    float bias = b1[colg];
    #pragma unroll
    for (int i = 0; i < 4; ++i) {
      int row = mt * 16 + quad * 4 + i;
      RC[row * 256 + (colg ^ ((row & 7) << 2))] = (f16)tanh_fast(acc[i] + bias);
    }
  }
  __syncthreads();
  {
    uint2* db = (uint2*)RB;
    #pragma unroll
    for (int k = 0; k < 2; ++k) {
      int idx = k * 512 + tid;
      if (idx < 640) {
        int row = idx >> 3, k4 = idx & 7;
        db[row * 8 + (k4 ^ (row & 7))] = pfh[k];
      }
    }
    uint2* dst = (uint2*)RW;
    #pragma unroll
    for (int k = 0; k < 8; ++k) {
      int idx = k * 512 + tid;
      int row = idx >> 6, k4 = idx & 63;
      dst[row * 64 + (k4 ^ (row & 7))] = pf[k];
    }
    const uint2* s2 = (const uint2*)(W2T + 16384);
    #pragma unroll
    for (int k = 0; k < 8; ++k) pf[k] = s2[k * 512 + tid];
  }
  __syncthreads();
  // fy half 0
  for (int tt = wv; tt < 8; tt += 8) {
    int mt = tt >> 2, nt = tt & 3;
    f32x4 acc = {0.f, 0.f, 0.f, 0.f};
    #pragma unroll
    for (int kk = 0; kk < 16; ++kk) {
      f16x4 av = ldfrag(RC, mt * 16 + r, 64, kk, quad);
      f16x4 bv = ldfrag(RW, nt * 16 + r, 64, kk, quad);
      acc = __builtin_amdgcn_mfma_f32_16x16x16f16(av, bv, acc, 0, 0, 0);
    }
    int jg = nt * 16 + r;
    float bias = b2[jg];
    #pragma unroll
    for (int i = 0; i < 4; ++i) {
      int n = mt * 16 + quad * 4 + i;
      RA[jg * 32 + (n ^ ((jg & 7) << 2))] = (f16)(acc[i] + bias);
    }
  }
  __syncthreads();
  {
    uint2* dst = (uint2*)RW;
    #pragma unroll
    for (int k = 0; k < 8; ++k) {
      int idx = k * 512 + tid;
      int row = idx >> 6, k4 = idx & 63;
      dst[row * 64 + (k4 ^ (row & 7))] = pf[k];
    }
  }
  __syncthreads();
  // fy half 1
  for (int tt = wv; tt < 8; tt += 8) {
    int mt = tt >> 2, nt = tt & 3;
    f32x4 acc = {0.f, 0.f, 0.f, 0.f};
    #pragma unroll
    for (int kk = 0; kk < 16; ++kk) {
      f16x4 av = ldfrag(RC, mt * 16 + r, 64, kk, quad);
      f16x4 bv = ldfrag(RW, nt * 16 + r, 64, kk, quad);
      acc = __builtin_amdgcn_mfma_f32_16x16x16f16(av, bv, acc, 0, 0, 0);
    }
    int jg = 64 + nt * 16 + r;
    float bias = b2[jg];
    #pragma unroll
    for (int i = 0; i < 4; ++i) {
      int n = mt * 16 + quad * 4 + i;
      RA[jg * 32 + (n ^ ((jg & 7) << 2))] = (f16)(acc[i] + bias);
    }
  }
  __syncthreads();
  // S[80][128] = hdw @ fy, stored chunk-major to Sq
  for (int tt = wv; tt < 40; tt += 8) {
    int mt = tt >> 3, nt = tt & 7;
    f32x4 acc = {0.f, 0.f, 0.f, 0.f};
    #pragma unroll
    for (int kk = 0; kk < 2; ++kk) {
      f16x4 av = ldfrag(RB, mt * 16 + r, 8, kk, quad);
      f16x4 bv = ldfrag(RA, nt * 16 + r, 8, kk, quad);
      acc = __builtin_amdgcn_mfma_f32_16x16x16f16(av, bv, acc, 0, 0, 0);
    }
    #pragma unroll
    for (int i = 0; i < 4; ++i) {
      int c = mt * 16 + quad * 4 + i;
      if (c < 65) {
        int col = nt * 16 + r;
        int kcS = c / 5;
        int kr = (c - kcS * 5) * 128 + col;
        Sq[kcS * 163840 + p * 640 + kr] = __float2half(acc[i]);
      }
    }
  }
}

// g += S @ WTC^T via MFMA; both operand streams CONTIGUOUS per block.
// Grid (16 m-tiles, 13 K-chunks of 640); 256 threads; last of 208 blocks
// runs the Simpson+cumsum epilogue (split-K completion via ctr).
__global__ __launch_bounds__(256) void k_gemmM(
    const __half* __restrict__ Sq, const __half* __restrict__ WTC,
    float* __restrict__ g, const float* __restrict__ t,
    const float* __restrict__ z0, __half* __restrict__ ygT,
    float* __restrict__ out, unsigned* __restrict__ ctr, int wout) {
  __shared__ __align__(16) unsigned char smem[65280];
  __shared__ unsigned lastFlag;
  uint2* Asw  = (uint2*)smem;                    // 2560 u = 20480 B
  uint2* Bsw0 = (uint2*)(smem + 20480);          // 2048 u = 16384 B
  uint2* Bsw1 = (uint2*)(smem + 36864);          // 2048 u = 16384 B
  int mt = blockIdx.x;      // 0..15
  int kc = blockIdx.y;      // 0..12
  int tid = threadIdx.x;
  int wv = tid >> 6, l = tid & 63, quad = l >> 4, r = l & 15;
  int p0 = mt * 16;
  int rowT = tid >> 4, u4lo = tid & 15;
  // stage A[16][640] once: contiguous 20 KB (16 adjacent 1280-B rows)
  {
    const uint2* srcA = (const uint2*)(Sq + kc * 163840 + (p0 + rowT) * 640) + u4lo;
    #pragma unroll
    for (int pass = 0; pass < 10; ++pass) {
      int u4 = pass * 16 + u4lo;
      Asw[rowT * 160 + (u4 ^ (rowT & 7))] = srcA[pass * 16];
    }
  }
  // B chunks: contiguous 16 KB each at WTC + (kc*10+kb)*8192 halves
  const uint2* bbase = (const uint2*)WTC + kc * 10 * 2048;
  #pragma unroll
  for (int pass = 0; pass < 8; ++pass) {
    int idx = pass * 256 + tid;
    int row = idx >> 4, u4 = idx & 15;
    Bsw0[row * 16 + (u4 ^ (row & 7))] = bbase[idx];
  }
  __syncthreads();
  f32x4 acc0 = {0.f, 0.f, 0.f, 0.f}, acc1 = {0.f, 0.f, 0.f, 0.f};
  int n0 = wv * 32;
  const f16* Af = (const f16*)Asw;
  for (int kb = 0; kb < 10; ++kb) {
    const f16* Bf = (const f16*)((kb & 1) ? Bsw1 : Bsw0);
    uint2* nxtB = (kb & 1) ? Bsw0 : Bsw1;
    uint2 pf[8];
    if (kb < 9) {   // prefetch next contiguous 16-KB chunk
      const uint2* srcN = bbase + (kb + 1) * 2048;
      #pragma unroll
      for (int pass = 0; pass < 8; ++pass) pf[pass] = srcN[pass * 256 + tid];
    }
    #pragma unroll
    for (int kk = 0; kk < 4; ++kk) {
      int kg4 = kb * 16 + kk * 4 + quad;
      f16x4 av = *(const f16x4*)(Af + 4 * (r * 160 + (kg4 ^ (r & 7))));
      int nr0 = n0 + r, nr1 = n0 + 16 + r;
      f16x4 b0 = *(const f16x4*)(Bf + 4 * (nr0 * 16 + ((kk * 4 + quad) ^ (nr0 & 7))));
      f16x4 b1 = *(const f16x4*)(Bf + 4 * (nr1 * 16 + ((kk * 4 + quad) ^ (nr1 & 7))));
      acc0 = __builtin_amdgcn_mfma_f32_16x16x16f16(av, b0, acc0, 0, 0, 0);
      acc1 = __builtin_amdgcn_mfma_f32_16x16x16f16(av, b1, acc1, 0, 0, 0);
    }
    if (kb < 9) {
      #pragma unroll
      for (int pass = 0; pass < 8; ++pass) {
        int idx = pass * 256 + tid;
        int row = idx >> 4, u4 = idx & 15;
        nxtB[row * 16 + (u4 ^ (row & 7))] = pf[pass];
      }
    }
    __syncthreads();
  }
  #pragma unroll
  for (int i = 0; i < 4; ++i) {
    int p = p0 + quad * 4 + i;
    if (p < 255) {
      atomicAdd(&g[p * 128 + n0 + r], acc0[i]);
      atomicAdd(&g[p * 128 + n0 + 16 + r], acc1[i]);
    }
  }
  // ---- tail-block epilogue (split-K completion pattern) ----
  __threadfence();
  if (tid == 0) {
    unsigned old = atomicAdd(ctr, 1u);
    lastFlag = (old == 207u) ? 1u : 0u;
    if (lastFlag) *ctr = 0u;
  }
  __syncthreads();
  if (!lastFlag) return;
  __threadfence();
  float* incL = (float*)smem;
  for (int idx = tid; idx < 127 * 128; idx += 256) {
    int k = idx >> 7, d = idx & 127;
    float tk = t[k], tk1 = t[k + 1];
    float h = tk1 - tk;
    float sct  = tk * (1.0f / 31.0f);
    float scm  = 0.5f * (tk + tk1) * (1.0f / 31.0f);
    float sct1 = tk1 * (1.0f / 31.0f);
    incL[idx] = h * (1.0f / 6.0f) *
        (g[k * 128 + d] * sct + 4.0f * g[(T_ + k) * 128 + d] * scm +
         g[(k + 1) * 128 + d] * sct1);
  }
  __syncthreads();
  if (tid < 128) {
    int d = tid;
    float acc = z0[d];
    ygT[d * 128] = __float2half(acc);
    if (wout) out[d] = acc;
    #pragma unroll 4
    for (int k = 0; k < 127; ++k) {
      acc += incL[k * 128 + d];
      ygT[d * 128 + k + 1] = __float2half(acc);
      if (wout) out[(k + 1) * 128 + d] = acc;
    }
  }
}

extern "C" void kernel_launch(void* const* d_in, const int* in_sizes, int n_in,
                              void* d_out, int out_size, void* d_ws, size_t ws_size,
                              hipStream_t stream) {
  const float* z0  = (const float*)d_in[0];
  const float* t   = (const float*)d_in[1];
  const float* W1  = (const float*)d_in[2];
  const float* b1  = (const float*)d_in[3];
  const float* W2  = (const float*)d_in[4];
  const float* b2  = (const float*)d_in[5];
  const float* Wk1 = (const float*)d_in[6];
  const float* bk1 = (const float*)d_in[7];
  const float* Wk2 = (const float*)d_in[8];
  const float* bk2 = (const float*)d_in[9];
  float* out = (float*)d_out;
  float* ws  = (float*)d_ws;

  __half*   ygT  = (__half*)(ws + OFF_YGT);
  float*    coef = ws + OFF_COEF;
  float*    Ainv = ws + OFF_AINV;
  __half*   E    = (__half*)(ws + OFF_E);
  __half*   HDW  = (__half*)(ws + OFF_HDW);
  __half*   W1T  = (__half*)(ws + OFF_W1T);
  __half*   W2T  = (__half*)(ws + OFF_W2T);
  __half*   WTC  = (__half*)(ws + OFF_WTT);
  __half*   Sq   = (__half*)(ws + OFF_S);
  float*    g    = ws + OFF_G2;
  unsigned* ctr  = (unsigned*)(ws + OFF_CTR);

  k_setup<<<dim3(256), dim3(256), 0, stream>>>(z0, t, W1, W2, Wk2, bk2,
                                               ygT, coef, Ainv, W1T, W2T, WTC,
                                               ctr);
  for (int it = 0; it < 3; ++it) {
    k_fused<<<dim3(255), dim3(512), 0, stream>>>(E, HDW, ygT, W1T, W2T,
                                                 b1, b2, Sq, g, t, Wk1, bk1,
                                                 coef, Ainv, it);
    k_gemmM<<<dim3(16, 13), dim3(256), 0, stream>>>(Sq, WTC, g, t, z0, ygT, out,
                                                    ctr, (it == 2) ? 1 : 0);
  }
}

// Round 18
// 167.384 us; speedup vs baseline: 1.2319x; 1.0763x over previous
//
#include <hip/hip_runtime.h>
#include <hip/hip_fp16.h>

// Problem constants
#define D_  128
#define T_  128
#define P_  255           // 2T-1 evaluation points
#define GSZ  32640        // 255*128

// workspace offsets (float slots)
#define OFF_YGF   0          // half ygF[16384] (fragment-major)   8192 f
#define OFF_COEF  8192       // float coef[512]
#define OFF_AINV  8704       // float Ainv[16384]
#define OFF_E     41472      // half EF[255*4096] (fragment-major) 522240 f
#define OFF_HDW   563712     // half HDW[255*2080]                 265200 f
#define OFF_W1F   828912     // half W1F[32768] (fragment-major)   16384 f
#define OFF_W2F   845296     // half W2F[32768] (fragment-major)   16384 f
#define OFF_WTT   861680     // half WTC[13][10][128][64]          532480 f
#define OFF_S     1394160    // half Sq[13][256][640]              1064960 f
#define OFF_G2    2459120    // float g[32640]
#define OFF_CTR   2491760    // unsigned ctr[1]
// end = 2491761 floats = 9.5 MiB

typedef _Float16 f16;
typedef _Float16 f16x4 __attribute__((ext_vector_type(4)));
typedef float f32x4 __attribute__((ext_vector_type(4)));

__device__ __forceinline__ float tanh_fast(float x) {
  float e = __expf(2.0f * x);
  return 1.0f - 2.0f / (e + 1.0f);
}

// Fragment read from swizzled row-major [rows][K] f16 LDS buffer.
__device__ __forceinline__ f16x4 ldfrag(const f16* buf, int row, int kunits,
                                        int kk, int quad) {
  int u = row * kunits + ((kk * 4 + quad) ^ (row & 7));
  return *(const f16x4*)(buf + 4 * u);
}

// ---- setup: ygF init, W1F/W2F fragment-major transposes, WTC relayout,
//      Thomas inverse ----
__global__ __launch_bounds__(256) void k_setup(
    const float* __restrict__ z0, const float* __restrict__ tgrid,
    const float* __restrict__ W1, const float* __restrict__ W2,
    const float* __restrict__ Wk2, const float* __restrict__ bk2,
    __half* __restrict__ ygF, float* __restrict__ coef,
    float* __restrict__ Ainv, __half* __restrict__ W1F,
    __half* __restrict__ W2F, __half* __restrict__ WTC,
    unsigned* __restrict__ ctr) {
  __shared__ __align__(16) unsigned char smem[66560];
  int bid = blockIdx.x, tid = threadIdx.x;
  // WTC chunk-major (round-17 proven layout)
  for (int idx = bid * 256 + tid; idx < 65 * 16384; idx += 256 * 256) {
    int c = idx >> 14, rem = idx & 16383;
    int i = rem >> 7, j = rem & 127;
    float v = (c < 64) ? Wk2[idx] : bk2[rem];
    int kc = c / 5;
    int kr = (c - kc * 5) * 128 + j;
    int kb = kr >> 6, kw = kr & 63;
    WTC[(((kc * 10 + kb) << 7) + i) * 64 + kw] = __float2half(v);
  }
  if (bid == 0) {
    // ygF fragment-major: value depends only on d = nt*16 + (lane&15)
    for (int idx = tid; idx < 16384; idx += 256) {
      int l2 = (idx >> 2) & 63, blk = idx >> 8;
      int nt = blk >> 3, rr = l2 & 15;
      ygF[idx] = __float2half(z0[nt * 16 + rr]);
    }
  } else if (bid == 1) {
    // W1F[((nt*8+kk)*64+l)*4+j] = W1[d*256+c], c=nt*16+(l&15), d=kk*16+(l>>4)*4+j
    for (int idx = tid; idx < 32768; idx += 256) {
      int j = idx & 3, l2 = (idx >> 2) & 63, blk = idx >> 8;
      int nt = blk >> 3, kk = blk & 7, rr = l2 & 15, qd = l2 >> 4;
      int c = nt * 16 + rr, d = kk * 16 + qd * 4 + j;
      W1F[idx] = __float2half(W1[d * 256 + c]);
    }
  } else if (bid == 2) {
    // W2F[((nt*16+kk)*64+l)*4+j] = W2[c*128+jcol], jcol=nt*16+(l&15), c=kk*16+(l>>4)*4+j
    for (int idx = tid; idx < 32768; idx += 256) {
      int j = idx & 3, l2 = (idx >> 2) & 63, blk = idx >> 8;
      int nt = blk >> 4, kk = blk & 15, rr = l2 & 15, qd = l2 >> 4;
      int jcol = nt * 16 + rr, c = kk * 16 + qd * 4 + j;
      W2F[idx] = __float2half(W2[c * 128 + jcol]);
    }
  } else if (bid == 3) {
    if (tid == 0) *ctr = 0u;
  } else if (bid == 255) {   // tridiagonal inverse (Thomas per column)
    float* dpL = (float*)smem;              // 127*128 floats
    float* tl  = (float*)(smem + 65024);    // 128
    float* cpL = tl + 128;
    float* imL = cpL + 128;
    if (tid < 128) tl[tid] = tgrid[tid];
    __syncthreads();
    if (tid == 0) {
      cpL[0] = 0.0f;
      float cprev = 0.0f;
      for (int i = 1; i <= 126; ++i) {
        float hm = tl[i] - tl[i - 1], hi = tl[i + 1] - tl[i];
        float m = 2.0f * (hm + hi) - hm * cprev;
        float im = 1.0f / m;
        imL[i] = im;
        cprev = hi * im;
        cpL[i] = cprev;
      }
    }
    if (tid < 127) coef[256 + tid] = 1.0f / (tl[tid + 1] - tl[tid]);
    __syncthreads();
    if (tid < 128) {
      int d = tid;
      float dprev = (d == 0) ? 1.0f : 0.0f;
      dpL[d] = dprev;
      for (int i = 1; i <= 126; ++i) {
        float rhs = (i == d) ? 1.0f : 0.0f;
        float hm = tl[i] - tl[i - 1];
        dprev = (rhs - hm * dprev) * imL[i];
        dpL[i * 128 + d] = dprev;
      }
      float x = (d == 127) ? 1.0f : 0.0f;
      Ainv[127 * 128 + d] = x;
      for (int i = 126; i >= 0; --i) {
        x = dpL[i * 128 + d] - cpL[i] * x;
        Ainv[i * 128 + d] = x;
      }
    }
  }
}

// Fused per-p MFMA chain, 512 threads; weights consumed as fragment-major
// global loads (no LDS staging, 3 barriers). it==0 computes EF/HDW first.
__global__ __launch_bounds__(512) void k_fused(
    __half* __restrict__ EF, __half* __restrict__ HDW,
    const __half* __restrict__ ygF,
    const __half* __restrict__ W1F, const __half* __restrict__ W2F,
    const float* __restrict__ b1, const float* __restrict__ b2,
    __half* __restrict__ Sq, float* __restrict__ g,
    const float* __restrict__ tgrid, const float* __restrict__ Wk1,
    const float* __restrict__ bk1, const float* __restrict__ coef,
    const float* __restrict__ Ainv, int it) {
  __shared__ __align__(16) unsigned char smem[32768];
  __shared__ float tl[128], ihL[128];
  __shared__ float sn[32], an[32], bn[32], cA[32], cB[32];
  __shared__ int idn[32];
  f16* RA = (f16*)smem;              // 4096 h: fyT[128 j][32 n]
  f16* RB = (f16*)(smem + 8192);     // 4096 h: ys[32][128] -> hdw[80][32]
  f16* RC = (f16*)(smem + 16384);    // 8192 h: h1[32][256]
  int p = blockIdx.x, tid = threadIdx.x;
  int wv = tid >> 6, l = tid & 63, quad = l >> 4, r = l & 15;

  if (tid < 128) g[p * 128 + tid] = 0.0f;
  if (p == 0) {   // zero the p=255 pad rows in every chunk
    for (int z = tid; z < 8320; z += 512) {
      int kcS = z / 640, kr = z - kcS * 640;
      Sq[kcS * 163840 + 255 * 640 + kr] = __float2half(0.0f);
    }
  }

  // ---- it==0 prologue: EF (fragment-major) + wq-folded hden ----
  if (it == 0) {
    if (tid < 128) tl[tid] = tgrid[tid];
    if (tid < 127) ihL[tid] = coef[256 + tid];
    __syncthreads();
    float xp = (p < T_) ? tl[p] : 0.5f * (tl[p - T_] + tl[p - T_ + 1]);
    if (tid < 32) {
      int n = tid;
      float u = (float)n * (1.0f / 31.0f);
      float q = xp * u;
      float qc = fminf(fmaxf(q, tl[0]), tl[127]);
      int i = (int)floorf(qc * 127.0f);
      i = max(0, min(126, i));
      while (i > 0 && qc < tl[i]) --i;
      while (i < 126 && qc >= tl[i + 1]) ++i;
      float h = tl[i + 1] - tl[i];
      float aa = (tl[i + 1] - qc) / h, bb = (qc - tl[i]) / h;
      sn[n] = q; idn[n] = i; an[n] = aa; bn[n] = bb;
      float h26 = h * h * (1.0f / 6.0f);
      cA[n] = (aa * aa * aa - aa) * h26;
      cB[n] = (bb * bb * bb - bb) * h26;
    }
    __syncthreads();
    #pragma unroll
    for (int pass = 0; pass < 8; ++pass) {
      int n = pass * 4 + (tid >> 7);
      int b = tid & 127;
      int i = idn[n];
      float Gi = 0.0f, Gi1 = 0.0f;
      if (b >= 2) {
        float w = 6.0f * ihL[b - 1];
        Gi  += Ainv[i * 128 + b - 1] * w;
        Gi1 += Ainv[(i + 1) * 128 + b - 1] * w;
      }
      if (b >= 1 && b <= 126) {
        float w = -6.0f * (ihL[b - 1] + ihL[b]);
        Gi  += Ainv[i * 128 + b] * w;
        Gi1 += Ainv[(i + 1) * 128 + b] * w;
      }
      if (b <= 125) {
        float w = 6.0f * ihL[b];
        Gi  += Ainv[i * 128 + b + 1] * w;
        Gi1 += Ainv[(i + 1) * 128 + b + 1] * w;
      }
      float v = cA[n] * Gi + cB[n] * Gi1;
      if (b == i) v += an[n];
      if (b == i + 1) v += bn[n];
      // fragment-major store: row n, k b
      int mtE = n >> 4, rrE = n & 15;
      int kkE = b >> 4, qdE = (b >> 2) & 3, jE = b & 3;
      EF[p * 4096 + ((((mtE * 8 + kkE) * 64 + qdE * 16 + rrE)) << 2) + jE] =
          __float2half(v);
    }
    #pragma unroll
    for (int k = 0; k < 5; ++k) {
      int idx = k * 512 + tid;
      if (idx < 2080) {
        int c = idx >> 5, n = idx & 31;
        float wq = (n == 0 || n == 31) ? 0.5f : 1.0f;
        float v = (c < 64)
            ? wq * tanh_fast(fmaf(xp, Wk1[c], fmaf(sn[n], Wk1[64 + c], bk1[c])))
            : wq;
        HDW[p * 2080 + idx] = __float2half(v);
      }
    }
    __syncthreads();
  }

  // hdw prefetch (T14): consumed in fy phase
  uint2 pfh[2];
  {
    const uint2* sh_ = (const uint2*)(HDW + p * 2080);
    #pragma unroll
    for (int k = 0; k < 2; ++k) {
      int idx = k * 512 + tid;
      if (idx < 640) pfh[k] = (idx < 520) ? sh_[idx] : make_uint2(0u, 0u);
    }
  }
  // ---- ys[32][128] = E @ yg : A=EF, B=ygF (global frags) -> RB ----
  const f16* efp = (const f16*)EF + p * 4096;
  for (int tt = wv; tt < 16; tt += 8) {
    int mt = tt >> 3, nt = tt & 7;
    f32x4 acc = {0.f, 0.f, 0.f, 0.f};
    #pragma unroll
    for (int kk = 0; kk < 8; ++kk) {
      f16x4 av = *(const f16x4*)(efp + (((mt * 8 + kk) * 64 + l) << 2));
      f16x4 bv = *(const f16x4*)((const f16*)ygF + (((nt * 8 + kk) * 64 + l) << 2));
      acc = __builtin_amdgcn_mfma_f32_16x16x16f16(av, bv, acc, 0, 0, 0);
    }
    int col = nt * 16 + r;
    #pragma unroll
    for (int i = 0; i < 4; ++i) {
      int row = mt * 16 + quad * 4 + i;
      RB[row * 128 + (col ^ ((row & 7) << 2))] = (f16)acc[i];
    }
  }
  __syncthreads();
  // ---- h1[32][256] = tanh(ys @ W1 + b1): A=RB, B=W1F (global) -> RC ----
  for (int tt = wv; tt < 32; tt += 8) {
    int mt = tt >> 4, nt = tt & 15;
    f32x4 acc = {0.f, 0.f, 0.f, 0.f};
    #pragma unroll
    for (int kk = 0; kk < 8; ++kk) {
      f16x4 av = ldfrag(RB, mt * 16 + r, 32, kk, quad);
      f16x4 bv = *(const f16x4*)((const f16*)W1F + (((nt * 8 + kk) * 64 + l) << 2));
      acc = __builtin_amdgcn_mfma_f32_16x16x16f16(av, bv, acc, 0, 0, 0);
    }
    int colg = nt * 16 + r;
    float bias = b1[colg];
    #pragma unroll
    for (int i = 0; i < 4; ++i) {
      int row = mt * 16 + quad * 4 + i;
      RC[row * 256 + (colg ^ ((row & 7) << 2))] = (f16)tanh_fast(acc[i] + bias);
    }
  }
  __syncthreads();
  // ---- fy: A=RC, B=W2F (global) -> RA (fyT); hdw regs -> RB ----
  {
    uint2* db = (uint2*)RB;
    #pragma unroll
    for (int k = 0; k < 2; ++k) {
      int idx = k * 512 + tid;
      if (idx < 640) {
        int row = idx >> 3, k4 = idx & 7;
        db[row * 8 + (k4 ^ (row & 7))] = pfh[k];
      }
    }
  }
  for (int tt = wv; tt < 16; tt += 8) {
    int mt = tt >> 3, nt = tt & 7;
    f32x4 acc = {0.f, 0.f, 0.f, 0.f};
    #pragma unroll
    for (int kk = 0; kk < 16; ++kk) {
      f16x4 av = ldfrag(RC, mt * 16 + r, 64, kk, quad);
      f16x4 bv = *(const f16x4*)((const f16*)W2F + (((nt * 16 + kk) * 64 + l) << 2));
      acc = __builtin_amdgcn_mfma_f32_16x16x16f16(av, bv, acc, 0, 0, 0);
    }
    int jg = nt * 16 + r;
    float bias = b2[jg];
    #pragma unroll
    for (int i = 0; i < 4; ++i) {
      int n = mt * 16 + quad * 4 + i;
      RA[jg * 32 + (n ^ ((jg & 7) << 2))] = (f16)(acc[i] + bias);
    }
  }
  __syncthreads();
  // ---- S[80][128] = hdw @ fy, stored chunk-major to Sq ----
  for (int tt = wv; tt < 40; tt += 8) {
    int mt = tt >> 3, nt = tt & 7;
    f32x4 acc = {0.f, 0.f, 0.f, 0.f};
    #pragma unroll
    for (int kk = 0; kk < 2; ++kk) {
      f16x4 av = ldfrag(RB, mt * 16 + r, 8, kk, quad);
      f16x4 bv = ldfrag(RA, nt * 16 + r, 8, kk, quad);
      acc = __builtin_amdgcn_mfma_f32_16x16x16f16(av, bv, acc, 0, 0, 0);
    }
    #pragma unroll
    for (int i = 0; i < 4; ++i) {
      int c = mt * 16 + quad * 4 + i;
      if (c < 65) {
        int col = nt * 16 + r;
        int kcS = c / 5;
        int kr = (c - kcS * 5) * 128 + col;
        Sq[kcS * 163840 + p * 640 + kr] = __float2half(acc[i]);
      }
    }
  }
}

// g += S @ WTC^T via MFMA; both operand streams CONTIGUOUS per block.
// Grid (16 m-tiles, 13 K-chunks of 640); 256 threads; last of 208 blocks
// runs the Simpson+cumsum epilogue (split-K completion via ctr).
__global__ __launch_bounds__(256) void k_gemmM(
    const __half* __restrict__ Sq, const __half* __restrict__ WTC,
    float* __restrict__ g, const float* __restrict__ t,
    const float* __restrict__ z0, __half* __restrict__ ygF,
    float* __restrict__ out, unsigned* __restrict__ ctr, int wout) {
  __shared__ __align__(16) unsigned char smem[65280];
  __shared__ unsigned lastFlag;
  uint2* Asw  = (uint2*)smem;                    // 2560 u = 20480 B
  uint2* Bsw0 = (uint2*)(smem + 20480);          // 2048 u = 16384 B
  uint2* Bsw1 = (uint2*)(smem + 36864);          // 2048 u = 16384 B
  int mt = blockIdx.x;      // 0..15
  int kc = blockIdx.y;      // 0..12
  int tid = threadIdx.x;
  int wv = tid >> 6, l = tid & 63, quad = l >> 4, r = l & 15;
  int p0 = mt * 16;
  int rowT = tid >> 4, u4lo = tid & 15;
  // stage A[16][640] once: contiguous 20 KB
  {
    const uint2* srcA = (const uint2*)(Sq + kc * 163840 + (p0 + rowT) * 640) + u4lo;
    #pragma unroll
    for (int pass = 0; pass < 10; ++pass) {
      int u4 = pass * 16 + u4lo;
      Asw[rowT * 160 + (u4 ^ (rowT & 7))] = srcA[pass * 16];
    }
  }
  // B chunks: contiguous 16 KB each
  const uint2* bbase = (const uint2*)WTC + kc * 10 * 2048;
  #pragma unroll
  for (int pass = 0; pass < 8; ++pass) {
    int idx = pass * 256 + tid;
    int row = idx >> 4, u4 = idx & 15;
    Bsw0[row * 16 + (u4 ^ (row & 7))] = bbase[idx];
  }
  __syncthreads();
  f32x4 acc0 = {0.f, 0.f, 0.f, 0.f}, acc1 = {0.f, 0.f, 0.f, 0.f};
  int n0 = wv * 32;
  const f16* Af = (const f16*)Asw;
  for (int kb = 0; kb < 10; ++kb) {
    const f16* Bf = (const f16*)((kb & 1) ? Bsw1 : Bsw0);
    uint2* nxtB = (kb & 1) ? Bsw0 : Bsw1;
    uint2 pf[8];
    if (kb < 9) {
      const uint2* srcN = bbase + (kb + 1) * 2048;
      #pragma unroll
      for (int pass = 0; pass < 8; ++pass) pf[pass] = srcN[pass * 256 + tid];
    }
    #pragma unroll
    for (int kk = 0; kk < 4; ++kk) {
      int kg4 = kb * 16 + kk * 4 + quad;
      f16x4 av = *(const f16x4*)(Af + 4 * (r * 160 + (kg4 ^ (r & 7))));
      int nr0 = n0 + r, nr1 = n0 + 16 + r;
      f16x4 b0 = *(const f16x4*)(Bf + 4 * (nr0 * 16 + ((kk * 4 + quad) ^ (nr0 & 7))));
      f16x4 b1 = *(const f16x4*)(Bf + 4 * (nr1 * 16 + ((kk * 4 + quad) ^ (nr1 & 7))));
      acc0 = __builtin_amdgcn_mfma_f32_16x16x16f16(av, b0, acc0, 0, 0, 0);
      acc1 = __builtin_amdgcn_mfma_f32_16x16x16f16(av, b1, acc1, 0, 0, 0);
    }
    if (kb < 9) {
      #pragma unroll
      for (int pass = 0; pass < 8; ++pass) {
        int idx = pass * 256 + tid;
        int row = idx >> 4, u4 = idx & 15;
        nxtB[row * 16 + (u4 ^ (row & 7))] = pf[pass];
      }
    }
    __syncthreads();
  }
  #pragma unroll
  for (int i = 0; i < 4; ++i) {
    int p = p0 + quad * 4 + i;
    if (p < 255) {
      atomicAdd(&g[p * 128 + n0 + r], acc0[i]);
      atomicAdd(&g[p * 128 + n0 + 16 + r], acc1[i]);
    }
  }
  // ---- tail-block epilogue (split-K completion pattern) ----
  __threadfence();
  if (tid == 0) {
    unsigned old = atomicAdd(ctr, 1u);
    lastFlag = (old == 207u) ? 1u : 0u;
    if (lastFlag) *ctr = 0u;
  }
  __syncthreads();
  if (!lastFlag) return;
  __threadfence();
  float* incL = (float*)smem;
  for (int idx = tid; idx < 127 * 128; idx += 256) {
    int k = idx >> 7, d = idx & 127;
    float tk = t[k], tk1 = t[k + 1];
    float h = tk1 - tk;
    float sct  = tk * (1.0f / 31.0f);
    float scm  = 0.5f * (tk + tk1) * (1.0f / 31.0f);
    float sct1 = tk1 * (1.0f / 31.0f);
    incL[idx] = h * (1.0f / 6.0f) *
        (g[k * 128 + d] * sct + 4.0f * g[(T_ + k) * 128 + d] * scm +
         g[(k + 1) * 128 + d] * sct1);
  }
  __syncthreads();
  if (tid < 128) {
    int d = tid, ntF = d >> 4, rrF = d & 15;
    float acc = z0[d];
    ygF[((ntF * 8) * 64 + rrF) << 2] = __float2half(acc);   // k=0
    if (wout) out[d] = acc;
    #pragma unroll 4
    for (int k = 0; k < 127; ++k) {
      acc += incL[k * 128 + d];
      int kp = k + 1;
      int kkF = kp >> 4, qdF = (kp >> 2) & 3, jF = kp & 3;
      ygF[((((ntF * 8 + kkF) * 64 + qdF * 16 + rrF)) << 2) + jF] =
          __float2half(acc);
      if (wout) out[kp * 128 + d] = acc;
    }
  }
}

extern "C" void kernel_launch(void* const* d_in, const int* in_sizes, int n_in,
                              void* d_out, int out_size, void* d_ws, size_t ws_size,
                              hipStream_t stream) {
  const float* z0  = (const float*)d_in[0];
  const float* t   = (const float*)d_in[1];
  const float* W1  = (const float*)d_in[2];
  const float* b1  = (const float*)d_in[3];
  const float* W2  = (const float*)d_in[4];
  const float* b2  = (const float*)d_in[5];
  const float* Wk1 = (const float*)d_in[6];
  const float* bk1 = (const float*)d_in[7];
  const float* Wk2 = (const float*)d_in[8];
  const float* bk2 = (const float*)d_in[9];
  float* out = (float*)d_out;
  float* ws  = (float*)d_ws;

  __half*   ygF  = (__half*)(ws + OFF_YGF);
  float*    coef = ws + OFF_COEF;
  float*    Ainv = ws + OFF_AINV;
  __half*   EF   = (__half*)(ws + OFF_E);
  __half*   HDW  = (__half*)(ws + OFF_HDW);
  __half*   W1F  = (__half*)(ws + OFF_W1F);
  __half*   W2F  = (__half*)(ws + OFF_W2F);
  __half*   WTC  = (__half*)(ws + OFF_WTT);
  __half*   Sq   = (__half*)(ws + OFF_S);
  float*    g    = ws + OFF_G2;
  unsigned* ctr  = (unsigned*)(ws + OFF_CTR);

  k_setup<<<dim3(256), dim3(256), 0, stream>>>(z0, t, W1, W2, Wk2, bk2,
                                               ygF, coef, Ainv, W1F, W2F, WTC,
                                               ctr);
  for (int it = 0; it < 3; ++it) {
    k_fused<<<dim3(255), dim3(512), 0, stream>>>(EF, HDW, ygF, W1F, W2F,
                                                 b1, b2, Sq, g, t, Wk1, bk1,
                                                 coef, Ainv, it);
    k_gemmM<<<dim3(16, 13), dim3(256), 0, stream>>>(Sq, WTC, g, t, z0, ygF, out,
                                                    ctr, (it == 2) ? 1 : 0);
  }
}